// Round 3
// baseline (310.325 us; speedup 1.0000x reference)
//
#include <hip/hip_runtime.h>
#include <hip/hip_bf16.h>
#include <math.h>

typedef __bf16 bf16x8 __attribute__((ext_vector_type(8)));
typedef float f32x4 __attribute__((ext_vector_type(4)));

__device__ __forceinline__ __hip_bfloat16 f2bf(float v){ return __float2bfloat16(v); }

// async global->LDS, 16B per lane; LDS dest must be wave-uniform base (lane writes base+lane*16)
__device__ __forceinline__ void gload16(const void* g, void* l){
  __builtin_amdgcn_global_load_lds(
      (const __attribute__((address_space(1))) void*)g,
      (__attribute__((address_space(3))) void*)l, 16, 0, 0);
}

// ---------------- weight transpose+convert: in f32[K][N] -> out bf16[N][K] ----------------
__global__ void transpose_f2b(const float* __restrict__ in,
                              __hip_bfloat16* __restrict__ out, int K, int N){
  __shared__ float tile[32][33];
  int tx = threadIdx.x, ty = threadIdx.y;
  int n0 = blockIdx.x*32, k0 = blockIdx.y*32;
#pragma unroll
  for(int i=0;i<4;i++) tile[ty+i*8][tx] = in[(size_t)(k0+ty+i*8)*N + n0+tx];
  __syncthreads();
#pragma unroll
  for(int i=0;i<4;i++) out[(size_t)(n0+ty+i*8)*K + k0+tx] = f2bf(tile[tx][ty+i*8]);
}

// ---------------- LayerNorm over C=768, one row per block; f32 in -> bf16 out ----------------
__global__ __launch_bounds__(256) void ln_kernel(const float* __restrict__ in,
    const float* __restrict__ g, const float* __restrict__ b,
    __hip_bfloat16* __restrict__ out){
  int row = blockIdx.x, t = threadIdx.x;
  const float* rp = in + (size_t)row*768;
  float x0 = rp[t], x1 = rp[t+256], x2 = rp[t+512];
  float s = x0+x1+x2, ss = x0*x0+x1*x1+x2*x2;
#pragma unroll
  for(int o=32;o>0;o>>=1){ s += __shfl_down(s,o); ss += __shfl_down(ss,o); }
  __shared__ float red[10];
  if((t&63)==0){ red[t>>6]=s; red[4+(t>>6)]=ss; }
  __syncthreads();
  if(t==0){
    float S=red[0]+red[1]+red[2]+red[3], SS=red[4]+red[5]+red[6]+red[7];
    float m=S*(1.f/768.f);
    red[8]=m; red[9]=SS*(1.f/768.f)-m*m;
  }
  __syncthreads();
  float m=red[8], r=rsqrtf(red[9]+1e-5f);
  __hip_bfloat16* op = out + (size_t)row*768;
  op[t]     = f2bf((x0-m)*r*g[t]     + b[t]);
  op[t+256] = f2bf((x1-m)*r*g[t+256] + b[t+256]);
  op[t+512] = f2bf((x2-m)*r*g[t+512] + b[t+512]);
}

// ---------------- GEMM (m97 structure): C[M][N] = A[M][K] * BT[N][K]^T, global_load_lds staging ----
// BN=128, BK=64. BM=128 (waves 2x2, frag 4x4) or BM=64 (waves 1x4, frag 4x2).
// EPI: 0=*0.125->bf16 (Q pre-scale)  1=KV split (+tem f32 on V)  2=+resid(f32)->f32  3=gelu->bf16  4=+resid(f32)->f32
template<int BM, int EPI>
__global__ __launch_bounds__(256) void gemm_gl(
    const __hip_bfloat16* __restrict__ A, const __hip_bfloat16* __restrict__ BT,
    const float* __restrict__ bias, int M, int N, int K,
    void* __restrict__ out, const void* __restrict__ aux0, void* __restrict__ out2){
  constexpr int NF = (BM==128)?4:2;
  __shared__ char sA[BM*128];    // [row][64 bf16] linear (gload_lds requires linear dest)
  __shared__ char sB[128*128];
  const int tid = threadIdx.x;
  const int l = tid & 63, w = tid >> 6;
  const int lg = l >> 4, li = l & 15;
  const int wrow = (BM==128)? (w>>1)*64 : 0;
  const int wcol = (BM==128)? (w&1)*64 : w*32;
  const int bm = blockIdx.x * BM;
  const int bn = blockIdx.y * 128;
  const int arow = w*(BM/4) + (l>>3);   // staging rows
  const int brow = w*32 + (l>>3);
  const int acol = (l&7)*8;             // staging col (elements)

  f32x4 acc[4][NF] = {};
  const int nk = K >> 6;
  for(int kt=0; kt<nk; ++kt){
    const int k0 = kt*64;
#pragma unroll
    for(int i=0;i<BM/32;i++)
      gload16(A  + (size_t)(bm+arow+i*8)*K + k0 + acol, sA + (w*(BM/4))*128 + i*1024);
#pragma unroll
    for(int i=0;i<4;i++)
      gload16(BT + (size_t)(bn+brow+i*8)*K + k0 + acol, sB + (w*32)*128 + i*1024);
    __syncthreads();
#pragma unroll
    for(int kk=0;kk<2;kk++){
      const int kb = kk*64 + lg*16;
      bf16x8 af[4], bfr[NF];
#pragma unroll
      for(int m=0;m<4;m++) af[m] = *(const bf16x8*)(sA + (wrow+m*16+li)*128 + kb);
#pragma unroll
      for(int n=0;n<NF;n++) bfr[n] = *(const bf16x8*)(sB + (wcol+n*16+li)*128 + kb);
#pragma unroll
      for(int m=0;m<4;m++)
#pragma unroll
        for(int n=0;n<NF;n++)
          acc[m][n] = __builtin_amdgcn_mfma_f32_16x16x32_bf16(af[m], bfr[n], acc[m][n],0,0,0);
    }
    __syncthreads();
  }
#pragma unroll
  for(int m=0;m<4;m++){
#pragma unroll
    for(int n=0;n<NF;n++){
#pragma unroll
      for(int r=0;r<4;r++){
        int row = bm + wrow + m*16 + lg*4 + r;
        int col = bn + wcol + n*16 + li;
        float v = acc[m][n][r] + bias[col];
        if constexpr(EPI==0){
          ((__hip_bfloat16*)out)[(size_t)row*N + col] = f2bf(v * 0.125f);
        } else if constexpr(EPI==1){
          if(col < 768){
            ((__hip_bfloat16*)out)[(size_t)row*768 + col] = f2bf(v);
          } else {
            int c = col - 768;
            int bb = row / 1344, ii = row % 1344;
            if(ii < 320) v += ((const float*)aux0)[((size_t)bb*320 + ii)*768 + c];
            ((__hip_bfloat16*)out2)[(size_t)row*768 + c] = f2bf(v);
          }
        } else if constexpr(EPI==2){
          v += ((const float*)aux0)[(size_t)row*N + col];
          ((float*)out)[(size_t)row*N + col] = v;
        } else if constexpr(EPI==3){
          float gl = 0.5f * v * (1.0f + erff(v * 0.70710678118654752f));
          ((__hip_bfloat16*)out)[(size_t)row*N + col] = f2bf(gl);
        } else {
          v += ((const float*)aux0)[(size_t)row*N + col];
          ((float*)out)[(size_t)row*N + col] = v;
        }
      }
    }
  }
}

// ---------------- fused attention: one block per (b, h, 64-row Q tile), dbuf + prefetch ----------------
__global__ __launch_bounds__(256) void attn_kernel(
    const __hip_bfloat16* __restrict__ qh,  // (B*LQ, 768), pre-scaled by 0.125
    const __hip_bfloat16* __restrict__ kb,  // (B*LKV, 768)
    const __hip_bfloat16* __restrict__ vb,  // (B*LKV, 768)
    const float* __restrict__ pos,          // (H, LQ, LKV) f32
    __hip_bfloat16* __restrict__ xo){       // (B*LQ, 768)
  __shared__ char sK[2][8192];     // K-tile row-major [kv][d], swizzled (reg-staged)
  __shared__ char sV[2][8192];     // V-tile transposed [d][kv], swizzled
  __shared__ char sP[4*2048];      // per-wave P tile [16][64], swizzled
  // XCD-bijective swizzle: 768 = 8 XCDs x 96; each XCD gets 6 whole (b,h) K/V sets (2MB -> L2-resident)
  const int bid = blockIdx.x;
  const int nbid = (bid & 7)*96 + (bid >> 3);
  const int qt = nbid & 15, h = (nbid >> 4) % 12, b = nbid / 192;
  const int q0 = qt * 64;
  const int tid = threadIdx.x;
  const int l = tid & 63, w = tid >> 6;
  const int lg = l >> 4, li = l & 15;
  const int srow = tid >> 3;           // staging row for item0 (0..31), item1 adds 32
  const int sslot = tid & 7;

  bf16x8 aq[2];
  {
    const char* qp = (const char*)(qh + ((size_t)(b*1024 + q0 + w*16 + li))*768 + h*64);
    aq[0] = *(const bf16x8*)(qp + lg*16);
    aq[1] = *(const bf16x8*)(qp + 64 + lg*16);
  }
  const size_t kvbase = (size_t)b*1344*768 + h*64;
  const size_t posbase = ((size_t)h*1024 + q0 + w*16 + lg*4)*1344;

  f32x4 accO[4] = {};
  float mrun[4], lrun[4];
#pragma unroll
  for(int r=0;r<4;r++){ mrun[r] = -1e30f; lrun[r] = 0.f; }

  // ---- prologue: load tile 0 (K/V to regs, pos to regs), write LDS buf0 ----
  uint4 pk[2], pv[2];
  float posr[4][4];
#pragma unroll
  for(int it=0; it<2; ++it){
    int row = srow + it*32;
    pk[it] = *(const uint4*)(kb + kvbase + (size_t)row*768 + sslot*8);
    pv[it] = *(const uint4*)(vb + kvbase + (size_t)row*768 + sslot*8);
  }
#pragma unroll
  for(int n=0;n<4;n++)
#pragma unroll
    for(int r=0;r<4;r++)
      posr[n][r] = pos[posbase + (size_t)r*1344 + n*16 + li];

  auto stage = [&](int buf, const uint4* k2, const uint4* v2){
#pragma unroll
    for(int it=0; it<2; ++it){
      int row = srow + it*32;
      *(uint4*)(sK[buf] + row*128 + ((sslot*16) ^ ((row&7)<<4))) = k2[it];
      const __hip_bfloat16* ue = (const __hip_bfloat16*)&v2[it];
#pragma unroll
      for(int i=0;i<8;i++){
        int d = sslot*8 + i;
        *(__hip_bfloat16*)(sV[buf] + d*128 + ((row*2) ^ ((d&7)<<4))) = ue[i];
      }
    }
  };
  stage(0, pk, pv);
  __syncthreads();

  for(int t=0; t<21; ++t){
    const int cur = t & 1;
    // S = Q K^T (Q pre-scaled by 1/8)
    f32x4 accS[4] = {};
#pragma unroll
    for(int kk=0; kk<2; ++kk){
      const int kbyte = kk*64 + lg*16;
#pragma unroll
      for(int n=0;n<4;n++){
        int row = n*16 + li;
        bf16x8 bkf = *(const bf16x8*)(sK[cur] + row*128 + (kbyte ^ ((row&7)<<4)));
        accS[n] = __builtin_amdgcn_mfma_f32_16x16x32_bf16(aq[kk], bkf, accS[n], 0,0,0);
      }
    }
    // prefetch tile t+1 (global -> regs); latency hides under softmax+PV
    uint4 nk_[2], nv_[2];
    float npos[4][4];
    if(t < 20){
      const size_t nb_ = kvbase + (size_t)(t+1)*64*768;
#pragma unroll
      for(int it=0; it<2; ++it){
        int row = srow + it*32;
        nk_[it] = *(const uint4*)(kb + nb_ + (size_t)row*768 + sslot*8);
        nv_[it] = *(const uint4*)(vb + nb_ + (size_t)row*768 + sslot*8);
      }
      const size_t pb = posbase + (size_t)(t+1)*64;
#pragma unroll
      for(int n=0;n<4;n++)
#pragma unroll
        for(int r=0;r<4;r++)
          npos[n][r] = pos[pb + (size_t)r*1344 + n*16 + li];
    }
    // softmax (online)
    float p[4][4], mt[4];
#pragma unroll
    for(int r=0;r<4;r++) mt[r] = -1e30f;
#pragma unroll
    for(int n=0;n<4;n++)
#pragma unroll
      for(int r=0;r<4;r++){
        float s = accS[n][r] + posr[n][r];
        p[n][r] = s;
        mt[r] = fmaxf(mt[r], s);
      }
    char* sPw = sP + w*2048;
#pragma unroll
    for(int r=0;r<4;r++){
#pragma unroll
      for(int o=1;o<16;o<<=1) mt[r] = fmaxf(mt[r], __shfl_xor(mt[r], o));
      float mnew = fmaxf(mrun[r], mt[r]);
      float sf = __expf(mrun[r]-mnew);
      mrun[r] = mnew;
      lrun[r] *= sf;
#pragma unroll
      for(int n=0;n<4;n++) accO[n][r] *= sf;
      float rs = 0.f;
#pragma unroll
      for(int n=0;n<4;n++){ p[n][r] = __expf(p[n][r]-mnew); rs += p[n][r]; }
#pragma unroll
      for(int o=1;o<16;o<<=1) rs += __shfl_xor(rs, o);
      lrun[r] += rs;
    }
    // write P tile (per wave)
#pragma unroll
    for(int n=0;n<4;n++)
#pragma unroll
      for(int r=0;r<4;r++){
        int qi = lg*4 + r, kj = n*16 + li;
        *(__hip_bfloat16*)(sPw + qi*128 + ((kj*2) ^ ((qi&7)<<4))) = f2bf(p[n][r]);
      }
    __syncthreads();   // P visible; prev readers of sK/sV[cur^1] done
    // O += P V
#pragma unroll
    for(int kk=0; kk<2; ++kk){
      const int kbyte = kk*64 + lg*16;
      bf16x8 pa = *(const bf16x8*)(sPw + li*128 + (kbyte ^ ((li&7)<<4)));
#pragma unroll
      for(int n=0;n<4;n++){
        int d = n*16 + li;
        bf16x8 bvf = *(const bf16x8*)(sV[cur] + d*128 + (kbyte ^ ((d&7)<<4)));
        accO[n] = __builtin_amdgcn_mfma_f32_16x16x32_bf16(pa, bvf, accO[n], 0,0,0);
      }
    }
    // write prefetched tile into the other buffer (no conflict with [cur] readers)
    if(t < 20){
      stage(cur^1, nk_, nv_);
#pragma unroll
      for(int n=0;n<4;n++)
#pragma unroll
        for(int r=0;r<4;r++) posr[n][r] = npos[n][r];
    }
    __syncthreads();   // t+1 LDS writes visible before next QK; sP safe to overwrite
  }
#pragma unroll
  for(int n=0;n<4;n++)
#pragma unroll
    for(int r=0;r<4;r++){
      int row = b*1024 + q0 + w*16 + lg*4 + r;
      int col = h*64 + n*16 + li;
      xo[(size_t)row*768 + col] = f2bf(accO[n][r] / lrun[r]);
    }
}

extern "C" void kernel_launch(void* const* d_in, const int* in_sizes, int n_in,
                              void* d_out, int out_size, void* d_ws, size_t ws_size,
                              hipStream_t stream){
  const float* tem   = (const float*)d_in[0];
  const float* qin   = (const float*)d_in[1];
  const float* kvin  = (const float*)d_in[2];
  const float* pos   = (const float*)d_in[3];
  const float* ln1qg = (const float*)d_in[4];
  const float* ln1qb = (const float*)d_in[5];
  const float* ln1kg = (const float*)d_in[6];
  const float* ln1kb = (const float*)d_in[7];
  const float* Wq    = (const float*)d_in[8];
  const float* bq    = (const float*)d_in[9];
  const float* Wkv   = (const float*)d_in[10];
  const float* bkv   = (const float*)d_in[11];
  const float* Wp    = (const float*)d_in[12];
  const float* bp    = (const float*)d_in[13];
  const float* ln2g  = (const float*)d_in[14];
  const float* ln2b  = (const float*)d_in[15];
  const float* W1    = (const float*)d_in[16];
  const float* b1    = (const float*)d_in[17];
  const float* W2    = (const float*)d_in[18];
  const float* b2    = (const float*)d_in[19];

  char* ws = (char*)d_ws; size_t off = 0;
  auto alloc = [&](size_t n){ char* p = ws + off; off = (off + n + 255) & ~(size_t)255; return p; };
  __hip_bfloat16* WqT  = (__hip_bfloat16*)alloc((size_t)768*768*2);
  __hip_bfloat16* WkvT = (__hip_bfloat16*)alloc((size_t)1536*768*2);
  __hip_bfloat16* WpT  = (__hip_bfloat16*)alloc((size_t)768*768*2);
  __hip_bfloat16* W1T  = (__hip_bfloat16*)alloc((size_t)3072*768*2);
  __hip_bfloat16* W2T  = (__hip_bfloat16*)alloc((size_t)768*3072*2);
  __hip_bfloat16* qn   = (__hip_bfloat16*)alloc((size_t)4096*768*2);
  char* poolBase = alloc((size_t)5376*768*2*3 + (size_t)4096*768*2); // kvn,kbuf,vbuf,qhb pool
  __hip_bfloat16* kvn  = (__hip_bfloat16*)poolBase;
  __hip_bfloat16* kbuf = kvn  + (size_t)5376*768;
  __hip_bfloat16* vbuf = kbuf + (size_t)5376*768;
  __hip_bfloat16* qhb  = vbuf + (size_t)5376*768;
  __hip_bfloat16* xat  = (__hip_bfloat16*)alloc((size_t)4096*768*2);
  float*          x1f  = (float*)alloc((size_t)4096*768*4);
  __hip_bfloat16* hln  = qn;    // qn dead after gemm<0>
  __hip_bfloat16* h1   = kvn;   // kvn/kbuf/vbuf/qhb dead after attn

  dim3 tb(32,8);
  transpose_f2b<<<dim3(768/32, 768/32),  tb, 0, stream>>>(Wq,  WqT,  768, 768);
  transpose_f2b<<<dim3(1536/32, 768/32), tb, 0, stream>>>(Wkv, WkvT, 768, 1536);
  transpose_f2b<<<dim3(768/32, 768/32),  tb, 0, stream>>>(Wp,  WpT,  768, 768);
  transpose_f2b<<<dim3(3072/32, 768/32), tb, 0, stream>>>(W1,  W1T,  768, 3072);
  transpose_f2b<<<dim3(768/32, 3072/32), tb, 0, stream>>>(W2,  W2T,  3072, 768);

  ln_kernel<<<4096, 256, 0, stream>>>(qin,  ln1qg, ln1qb, qn);
  ln_kernel<<<5376, 256, 0, stream>>>(kvin, ln1kg, ln1kb, kvn);

  gemm_gl<64,0> <<<dim3(64, 6),  256, 0, stream>>>(qn,  WqT,  bq,  4096, 768,  768,  qhb, nullptr, nullptr);
  gemm_gl<128,1><<<dim3(42, 12), 256, 0, stream>>>(kvn, WkvT, bkv, 5376, 1536, 768,  kbuf, tem, vbuf);

  attn_kernel<<<768, 256, 0, stream>>>(qhb, kbuf, vbuf, pos, xat);

  gemm_gl<64,2> <<<dim3(64, 6),  256, 0, stream>>>(xat, WpT,  bp,  4096, 768,  768,  x1f, qin, nullptr);
  ln_kernel<<<4096, 256, 0, stream>>>(x1f, ln2g, ln2b, hln);
  gemm_gl<128,3><<<dim3(32, 24), 256, 0, stream>>>(hln, W1T,  b1,  4096, 3072, 768,  h1, nullptr, nullptr);
  gemm_gl<64,4> <<<dim3(64, 6),  256, 0, stream>>>(h1,  W2T,  b2,  4096, 768,  3072, (float*)d_out, x1f, nullptr);
}

// Round 4
// 297.463 us; speedup vs baseline: 1.0432x; 1.0432x over previous
//
#include <hip/hip_runtime.h>
#include <hip/hip_bf16.h>
#include <math.h>

typedef __bf16 bf16x8 __attribute__((ext_vector_type(8)));
typedef float f32x4 __attribute__((ext_vector_type(4)));

__device__ __forceinline__ __hip_bfloat16 f2bf(float v){ return __float2bfloat16(v); }

// async global->LDS, 16B per lane; LDS dest is wave-uniform base (lane i writes base+i*16),
// global source is PER-LANE (swizzled layouts via pre-swizzled source addresses).
__device__ __forceinline__ void gload16(const void* g, void* l){
  __builtin_amdgcn_global_load_lds(
      (const __attribute__((address_space(1))) void*)g,
      (__attribute__((address_space(3))) void*)l, 16, 0, 0);
}

// ---------------- weight transpose+convert: in f32[K][N] -> out bf16[N][K] ----------------
__global__ void transpose_f2b(const float* __restrict__ in,
                              __hip_bfloat16* __restrict__ out, int K, int N){
  __shared__ float tile[32][33];
  int tx = threadIdx.x, ty = threadIdx.y;
  int n0 = blockIdx.x*32, k0 = blockIdx.y*32;
#pragma unroll
  for(int i=0;i<4;i++) tile[ty+i*8][tx] = in[(size_t)(k0+ty+i*8)*N + n0+tx];
  __syncthreads();
#pragma unroll
  for(int i=0;i<4;i++) out[(size_t)(n0+ty+i*8)*K + k0+tx] = f2bf(tile[tx][ty+i*8]);
}

// ---------------- V transpose: vbuf (B*1344, 768) -> vt (B*H*64, 1344) per (b,h) ----------------
__global__ __launch_bounds__(256) void transpose_vt(const __hip_bfloat16* __restrict__ vbuf,
                                                    __hip_bfloat16* __restrict__ vt){
  __shared__ __hip_bfloat16 tl[64][72];
  const int bh = blockIdx.x;      // 0..47
  const int kt = blockIdx.y;      // 0..20
  const int b = bh / 12, h = bh % 12;
  const int tid = threadIdx.x;
  const int r = tid >> 3, c = (tid & 7) * 8;
#pragma unroll
  for(int j=0;j<2;j++){
    uint4 v = *(const uint4*)(vbuf + ((size_t)(b*1344 + kt*64 + r + j*32))*768 + h*64 + c);
    *(uint4*)&tl[r + j*32][c] = v;
  }
  __syncthreads();
#pragma unroll
  for(int j=0;j<2;j++){
    int d = r + j*32;
    __hip_bfloat16 tmp[8];
#pragma unroll
    for(int i=0;i<8;i++) tmp[i] = tl[c + i][d];
    *(uint4*)(vt + ((size_t)(bh*64 + d))*1344 + kt*64 + c) = *(const uint4*)tmp;
  }
}

// ---------------- LayerNorm over C=768, one row per block; f32 in -> bf16 out ----------------
__global__ __launch_bounds__(256) void ln_kernel(const float* __restrict__ in,
    const float* __restrict__ g, const float* __restrict__ b,
    __hip_bfloat16* __restrict__ out){
  int row = blockIdx.x, t = threadIdx.x;
  const float* rp = in + (size_t)row*768;
  float x0 = rp[t], x1 = rp[t+256], x2 = rp[t+512];
  float s = x0+x1+x2, ss = x0*x0+x1*x1+x2*x2;
#pragma unroll
  for(int o=32;o>0;o>>=1){ s += __shfl_down(s,o); ss += __shfl_down(ss,o); }
  __shared__ float red[10];
  if((t&63)==0){ red[t>>6]=s; red[4+(t>>6)]=ss; }
  __syncthreads();
  if(t==0){
    float S=red[0]+red[1]+red[2]+red[3], SS=red[4]+red[5]+red[6]+red[7];
    float m=S*(1.f/768.f);
    red[8]=m; red[9]=SS*(1.f/768.f)-m*m;
  }
  __syncthreads();
  float m=red[8], r=rsqrtf(red[9]+1e-5f);
  __hip_bfloat16* op = out + (size_t)row*768;
  op[t]     = f2bf((x0-m)*r*g[t]     + b[t]);
  op[t+256] = f2bf((x1-m)*r*g[t+256] + b[t+256]);
  op[t+512] = f2bf((x2-m)*r*g[t+512] + b[t+512]);
}

// ---------------- GEMM (m97 structure): C[M][N] = A[M][K] * BT[N][K]^T, global_load_lds staging ----
// EPI: 0=*0.125->bf16  1=KV split (+tem f32 on V)  2=+resid(f32)->f32  3=gelu->bf16  4=+resid(f32)->f32
template<int BM, int EPI>
__global__ __launch_bounds__(256) void gemm_gl(
    const __hip_bfloat16* __restrict__ A, const __hip_bfloat16* __restrict__ BT,
    const float* __restrict__ bias, int M, int N, int K,
    void* __restrict__ out, const void* __restrict__ aux0, void* __restrict__ out2){
  constexpr int NF = (BM==128)?4:2;
  __shared__ char sA[BM*128];
  __shared__ char sB[128*128];
  const int tid = threadIdx.x;
  const int l = tid & 63, w = tid >> 6;
  const int lg = l >> 4, li = l & 15;
  const int wrow = (BM==128)? (w>>1)*64 : 0;
  const int wcol = (BM==128)? (w&1)*64 : w*32;
  const int bm = blockIdx.x * BM;
  const int bn = blockIdx.y * 128;
  const int arow = w*(BM/4) + (l>>3);
  const int brow = w*32 + (l>>3);
  const int acol = (l&7)*8;

  f32x4 acc[4][NF] = {};
  const int nk = K >> 6;
  for(int kt=0; kt<nk; ++kt){
    const int k0 = kt*64;
#pragma unroll
    for(int i=0;i<BM/32;i++)
      gload16(A  + (size_t)(bm+arow+i*8)*K + k0 + acol, sA + (w*(BM/4))*128 + i*1024);
#pragma unroll
    for(int i=0;i<4;i++)
      gload16(BT + (size_t)(bn+brow+i*8)*K + k0 + acol, sB + (w*32)*128 + i*1024);
    __syncthreads();
#pragma unroll
    for(int kk=0;kk<2;kk++){
      const int kb = kk*64 + lg*16;
      bf16x8 af[4], bfr[NF];
#pragma unroll
      for(int m=0;m<4;m++) af[m] = *(const bf16x8*)(sA + (wrow+m*16+li)*128 + kb);
#pragma unroll
      for(int n=0;n<NF;n++) bfr[n] = *(const bf16x8*)(sB + (wcol+n*16+li)*128 + kb);
#pragma unroll
      for(int m=0;m<4;m++)
#pragma unroll
        for(int n=0;n<NF;n++)
          acc[m][n] = __builtin_amdgcn_mfma_f32_16x16x32_bf16(af[m], bfr[n], acc[m][n],0,0,0);
    }
    __syncthreads();
  }
#pragma unroll
  for(int m=0;m<4;m++){
#pragma unroll
    for(int n=0;n<NF;n++){
#pragma unroll
      for(int r=0;r<4;r++){
        int row = bm + wrow + m*16 + lg*4 + r;
        int col = bn + wcol + n*16 + li;
        float v = acc[m][n][r] + bias[col];
        if constexpr(EPI==0){
          ((__hip_bfloat16*)out)[(size_t)row*N + col] = f2bf(v * 0.125f);
        } else if constexpr(EPI==1){
          if(col < 768){
            ((__hip_bfloat16*)out)[(size_t)row*768 + col] = f2bf(v);
          } else {
            int c = col - 768;
            int bb = row / 1344, ii = row % 1344;
            if(ii < 320) v += ((const float*)aux0)[((size_t)bb*320 + ii)*768 + c];
            ((__hip_bfloat16*)out2)[(size_t)row*768 + c] = f2bf(v);
          }
        } else if constexpr(EPI==2){
          v += ((const float*)aux0)[(size_t)row*N + col];
          ((float*)out)[(size_t)row*N + col] = v;
        } else if constexpr(EPI==3){
          float gl = 0.5f * v * (1.0f + erff(v * 0.70710678118654752f));
          ((__hip_bfloat16*)out)[(size_t)row*N + col] = f2bf(gl);
        } else {
          v += ((const float*)aux0)[(size_t)row*N + col];
          ((float*)out)[(size_t)row*N + col] = v;
        }
      }
    }
  }
}

// ---------------- fused attention: one block per (b, h, 64-row Q tile) ----------------
// K/V staged via global_load_lds with inverse-swizzled per-lane sources; single barrier per iter.
__global__ __launch_bounds__(256) void attn_kernel(
    const __hip_bfloat16* __restrict__ qh,  // (B*LQ, 768), pre-scaled by 0.125
    const __hip_bfloat16* __restrict__ kb,  // (B*LKV, 768)
    const __hip_bfloat16* __restrict__ vt,  // (B*H*64, 1344)  V transposed per (b,h)
    const float* __restrict__ pos,          // (H, LQ, LKV) f32
    __hip_bfloat16* __restrict__ xo){       // (B*LQ, 768)
  __shared__ char sK[2][8192];     // [kv][d] swizzled: byte x = d*2 ^ ((kv&7)<<4)
  __shared__ char sV[2][8192];     // [d][kv] swizzled: byte x = kv*2 ^ ((d&7)<<4)
  __shared__ char sP[4][2048];     // per-wave [q][kv] swizzled (wave-private)
  const int bid = blockIdx.x;
  const int qt = bid & 15, h = (bid >> 4) % 12, b = bid / 192;
  const int q0 = qt * 64;
  const int tid = threadIdx.x;
  const int l = tid & 63, w = tid >> 6;
  const int lg = l >> 4, li = l & 15;

  // staging geometry: linear LDS offset o = w*2048 + j*1024 + lane*16
  //   row = w*16 + j*8 + (l>>3); stored byte-in-row x = (l&7)*16;
  //   source element offset = (x ^ ((row&7)<<4))/2, (row&7) == (l>>3)
  const int srow = w*16 + (l>>3);
  const int soff = (((l&7)*16) ^ ((l>>3)<<4)) >> 1;
  const __hip_bfloat16* ksrc = kb + ((size_t)b*1344 + srow)*768 + h*64 + soff;
  const __hip_bfloat16* vsrc = vt + ((size_t)(b*12+h)*64 + srow)*1344 + soff;

  bf16x8 aq[2];
  {
    const char* qp = (const char*)(qh + ((size_t)(b*1024 + q0 + w*16 + li))*768 + h*64);
    aq[0] = *(const bf16x8*)(qp + lg*16);
    aq[1] = *(const bf16x8*)(qp + 64 + lg*16);
  }
  const size_t posbase = ((size_t)h*1024 + q0 + w*16 + lg*4)*1344 + li;

  f32x4 accO[4] = {};
  float mrun[4], lrun[4];
#pragma unroll
  for(int r=0;r<4;r++){ mrun[r] = -1e30f; lrun[r] = 0.f; }

  auto stage = [&](int buf, int t){
    const size_t ko = (size_t)t*64*768;   // K advances 64 rows
    const size_t vo = (size_t)t*64;       // V^T advances 64 columns
    gload16(ksrc + ko,          sK[buf] + w*2048);
    gload16(ksrc + ko + 8*768,  sK[buf] + w*2048 + 1024);
    gload16(vsrc + vo,          sV[buf] + w*2048);
    gload16(vsrc + vo + 8*1344, sV[buf] + w*2048 + 1024);
  };
  auto ldpos = [&](int t, float pr[4][4]){
    const float* pp = pos + posbase + (size_t)t*64;
#pragma unroll
    for(int n=0;n<4;n++)
#pragma unroll
      for(int r=0;r<4;r++)
        pr[n][r] = __builtin_nontemporal_load(pp + (size_t)r*1344 + n*16);
  };

  float posr[4][4];
  ldpos(0, posr);
  stage(0, 0);
  __syncthreads();   // drains gload vmcnt

  char* sPw = sP[w];
  for(int t=0; t<21; ++t){
    const int cur = t & 1;
    // S = Q K^T (Q pre-scaled by 1/8)
    f32x4 accS[4] = {};
#pragma unroll
    for(int kk=0; kk<2; ++kk){
      const int kbyte = kk*64 + lg*16;
#pragma unroll
      for(int n=0;n<4;n++){
        int row = n*16 + li;
        bf16x8 bkf = *(const bf16x8*)(sK[cur] + row*128 + (kbyte ^ ((row&7)<<4)));
        accS[n] = __builtin_amdgcn_mfma_f32_16x16x32_bf16(aq[kk], bkf, accS[n], 0,0,0);
      }
    }
    // issue next tile's staging now; softmax+PV cover the latency before the barrier drain
    if(t < 20) stage(cur^1, t+1);
    float npos[4][4];
    if(t < 20) ldpos(t+1, npos);

    // online softmax
    float p[4][4], mt[4];
#pragma unroll
    for(int r=0;r<4;r++) mt[r] = -1e30f;
#pragma unroll
    for(int n=0;n<4;n++)
#pragma unroll
      for(int r=0;r<4;r++){
        float s = accS[n][r] + posr[n][r];
        p[n][r] = s;
        mt[r] = fmaxf(mt[r], s);
      }
#pragma unroll
    for(int r=0;r<4;r++){
#pragma unroll
      for(int o=1;o<16;o<<=1) mt[r] = fmaxf(mt[r], __shfl_xor(mt[r], o));
      float mnew = fmaxf(mrun[r], mt[r]);
      float sf = __expf(mrun[r]-mnew);
      mrun[r] = mnew;
      lrun[r] *= sf;
#pragma unroll
      for(int n=0;n<4;n++) accO[n][r] *= sf;
      float rs = 0.f;
#pragma unroll
      for(int n=0;n<4;n++){ p[n][r] = __expf(p[n][r]-mnew); rs += p[n][r]; }
#pragma unroll
      for(int o=1;o<16;o<<=1) rs += __shfl_xor(rs, o);
      lrun[r] += rs;
    }
    // write P tile (wave-private: no barrier needed before PV)
#pragma unroll
    for(int n=0;n<4;n++)
#pragma unroll
      for(int r=0;r<4;r++){
        int qi = lg*4 + r, kj = n*16 + li;
        *(__hip_bfloat16*)(sPw + qi*128 + ((kj*2) ^ ((qi&7)<<4))) = f2bf(p[n][r]);
      }
    // O += P V
#pragma unroll
    for(int kk=0; kk<2; ++kk){
      const int kbyte = kk*64 + lg*16;
      bf16x8 pa = *(const bf16x8*)(sPw + li*128 + (kbyte ^ ((li&7)<<4)));
#pragma unroll
      for(int n=0;n<4;n++){
        int d = n*16 + li;
        bf16x8 bvf = *(const bf16x8*)(sV[cur] + d*128 + (kbyte ^ ((d&7)<<4)));
        accO[n] = __builtin_amdgcn_mfma_f32_16x16x32_bf16(pa, bvf, accO[n], 0,0,0);
      }
    }
    if(t < 20){
#pragma unroll
      for(int n=0;n<4;n++)
#pragma unroll
        for(int r=0;r<4;r++) posr[n][r] = npos[n][r];
    }
    __syncthreads();   // one barrier/iter: drains gloads (t+1 ready), syncs buffer reuse
  }
#pragma unroll
  for(int n=0;n<4;n++)
#pragma unroll
    for(int r=0;r<4;r++){
      int row = b*1024 + q0 + w*16 + lg*4 + r;
      int col = h*64 + n*16 + li;
      xo[(size_t)row*768 + col] = f2bf(accO[n][r] / lrun[r]);
    }
}

extern "C" void kernel_launch(void* const* d_in, const int* in_sizes, int n_in,
                              void* d_out, int out_size, void* d_ws, size_t ws_size,
                              hipStream_t stream){
  const float* tem   = (const float*)d_in[0];
  const float* qin   = (const float*)d_in[1];
  const float* kvin  = (const float*)d_in[2];
  const float* pos   = (const float*)d_in[3];
  const float* ln1qg = (const float*)d_in[4];
  const float* ln1qb = (const float*)d_in[5];
  const float* ln1kg = (const float*)d_in[6];
  const float* ln1kb = (const float*)d_in[7];
  const float* Wq    = (const float*)d_in[8];
  const float* bq    = (const float*)d_in[9];
  const float* Wkv   = (const float*)d_in[10];
  const float* bkv   = (const float*)d_in[11];
  const float* Wp    = (const float*)d_in[12];
  const float* bp    = (const float*)d_in[13];
  const float* ln2g  = (const float*)d_in[14];
  const float* ln2b  = (const float*)d_in[15];
  const float* W1    = (const float*)d_in[16];
  const float* b1    = (const float*)d_in[17];
  const float* W2    = (const float*)d_in[18];
  const float* b2    = (const float*)d_in[19];

  char* ws = (char*)d_ws; size_t off = 0;
  auto alloc = [&](size_t n){ char* p = ws + off; off = (off + n + 255) & ~(size_t)255; return p; };
  __hip_bfloat16* WqT  = (__hip_bfloat16*)alloc((size_t)768*768*2);
  __hip_bfloat16* WkvT = (__hip_bfloat16*)alloc((size_t)1536*768*2);
  __hip_bfloat16* WpT  = (__hip_bfloat16*)alloc((size_t)768*768*2);
  __hip_bfloat16* W1T  = (__hip_bfloat16*)alloc((size_t)3072*768*2);
  __hip_bfloat16* W2T  = (__hip_bfloat16*)alloc((size_t)768*3072*2);
  __hip_bfloat16* qn   = (__hip_bfloat16*)alloc((size_t)4096*768*2);
  char* poolBase = alloc((size_t)5376*768*2*3 + (size_t)4096*768*2); // kvn,kbuf,vbuf,qhb pool
  __hip_bfloat16* kvn  = (__hip_bfloat16*)poolBase;
  __hip_bfloat16* kbuf = kvn  + (size_t)5376*768;
  __hip_bfloat16* vbuf = kbuf + (size_t)5376*768;
  __hip_bfloat16* qhb  = vbuf + (size_t)5376*768;
  __hip_bfloat16* xat  = (__hip_bfloat16*)alloc((size_t)4096*768*2);
  float*          x1f  = (float*)alloc((size_t)4096*768*4);
  __hip_bfloat16* vt   = kvn;   // kvn dead after gemm<1>; vt (8.25MB) fits its 8.26MB slot
  __hip_bfloat16* hln  = qn;    // qn dead after gemm<0>
  __hip_bfloat16* h1   = kvn;   // whole pool dead after attn (h1 25.2MB fits 39.3MB pool)

  dim3 tb(32,8);
  transpose_f2b<<<dim3(768/32, 768/32),  tb, 0, stream>>>(Wq,  WqT,  768, 768);
  transpose_f2b<<<dim3(1536/32, 768/32), tb, 0, stream>>>(Wkv, WkvT, 768, 1536);
  transpose_f2b<<<dim3(768/32, 768/32),  tb, 0, stream>>>(Wp,  WpT,  768, 768);
  transpose_f2b<<<dim3(3072/32, 768/32), tb, 0, stream>>>(W1,  W1T,  768, 3072);
  transpose_f2b<<<dim3(768/32, 3072/32), tb, 0, stream>>>(W2,  W2T,  3072, 768);

  ln_kernel<<<4096, 256, 0, stream>>>(qin,  ln1qg, ln1qb, qn);
  ln_kernel<<<5376, 256, 0, stream>>>(kvin, ln1kg, ln1kb, kvn);

  gemm_gl<64,0> <<<dim3(64, 6),  256, 0, stream>>>(qn,  WqT,  bq,  4096, 768,  768,  qhb, nullptr, nullptr);
  gemm_gl<128,1><<<dim3(42, 12), 256, 0, stream>>>(kvn, WkvT, bkv, 5376, 1536, 768,  kbuf, tem, vbuf);
  transpose_vt<<<dim3(48, 21), 256, 0, stream>>>(vbuf, vt);

  attn_kernel<<<768, 256, 0, stream>>>(qhb, kbuf, vt, pos, xat);

  gemm_gl<64,2> <<<dim3(64, 6),  256, 0, stream>>>(xat, WpT,  bp,  4096, 768,  768,  x1f, qin, nullptr);
  ln_kernel<<<4096, 256, 0, stream>>>(x1f, ln2g, ln2b, hln);
  gemm_gl<128,3><<<dim3(32, 24), 256, 0, stream>>>(hln, W1T,  b1,  4096, 3072, 768,  h1, nullptr, nullptr);
  gemm_gl<64,4> <<<dim3(64, 6),  256, 0, stream>>>(h1,  W2T,  b2,  4096, 768,  3072, (float*)d_out, x1f, nullptr);
}

// Round 5
// 258.327 us; speedup vs baseline: 1.2013x; 1.1515x over previous
//
#include <hip/hip_runtime.h>
#include <hip/hip_bf16.h>
#include <math.h>

typedef __bf16 bf16x8 __attribute__((ext_vector_type(8)));
typedef float f32x4 __attribute__((ext_vector_type(4)));

__device__ __forceinline__ __hip_bfloat16 f2bf(float v){ return __float2bfloat16(v); }

// async global->LDS, 16B per lane; LDS dest is wave-uniform base (lane i writes base+i*16),
// global source is PER-LANE (swizzled layouts via pre-swizzled source addresses).
__device__ __forceinline__ void gload16(const void* g, void* l){
  __builtin_amdgcn_global_load_lds(
      (const __attribute__((address_space(1))) void*)g,
      (__attribute__((address_space(3))) void*)l, 16, 0, 0);
}

// ---------------- weight transpose+convert: in f32[K][N] -> out bf16[N][K] ----------------
__global__ void transpose_f2b(const float* __restrict__ in,
                              __hip_bfloat16* __restrict__ out, int K, int N){
  __shared__ float tile[32][33];
  int tx = threadIdx.x, ty = threadIdx.y;
  int n0 = blockIdx.x*32, k0 = blockIdx.y*32;
#pragma unroll
  for(int i=0;i<4;i++) tile[ty+i*8][tx] = in[(size_t)(k0+ty+i*8)*N + n0+tx];
  __syncthreads();
#pragma unroll
  for(int i=0;i<4;i++) out[(size_t)(n0+ty+i*8)*K + k0+tx] = f2bf(tile[tx][ty+i*8]);
}

// ---------------- V transpose: vbuf (B*1344, 768) -> vt (B*H*64, 1344) per (b,h) ----------------
__global__ __launch_bounds__(256) void transpose_vt(const __hip_bfloat16* __restrict__ vbuf,
                                                    __hip_bfloat16* __restrict__ vt){
  __shared__ __hip_bfloat16 tl[64][72];
  const int bh = blockIdx.x;      // 0..47
  const int kt = blockIdx.y;      // 0..20
  const int b = bh / 12, h = bh % 12;
  const int tid = threadIdx.x;
  const int r = tid >> 3, c = (tid & 7) * 8;
#pragma unroll
  for(int j=0;j<2;j++){
    uint4 v = *(const uint4*)(vbuf + ((size_t)(b*1344 + kt*64 + r + j*32))*768 + h*64 + c);
    *(uint4*)&tl[r + j*32][c] = v;
  }
  __syncthreads();
#pragma unroll
  for(int j=0;j<2;j++){
    int d = r + j*32;
    __hip_bfloat16 tmp[8];
#pragma unroll
    for(int i=0;i<8;i++) tmp[i] = tl[c + i][d];
    *(uint4*)(vt + ((size_t)(bh*64 + d))*1344 + kt*64 + c) = *(const uint4*)tmp;
  }
}

// ---------------- LayerNorm over C=768, one row per block; f32 in -> bf16 out ----------------
__global__ __launch_bounds__(256) void ln_kernel(const float* __restrict__ in,
    const float* __restrict__ g, const float* __restrict__ b,
    __hip_bfloat16* __restrict__ out){
  int row = blockIdx.x, t = threadIdx.x;
  const float* rp = in + (size_t)row*768;
  float x0 = rp[t], x1 = rp[t+256], x2 = rp[t+512];
  float s = x0+x1+x2, ss = x0*x0+x1*x1+x2*x2;
#pragma unroll
  for(int o=32;o>0;o>>=1){ s += __shfl_down(s,o); ss += __shfl_down(ss,o); }
  __shared__ float red[10];
  if((t&63)==0){ red[t>>6]=s; red[4+(t>>6)]=ss; }
  __syncthreads();
  if(t==0){
    float S=red[0]+red[1]+red[2]+red[3], SS=red[4]+red[5]+red[6]+red[7];
    float m=S*(1.f/768.f);
    red[8]=m; red[9]=SS*(1.f/768.f)-m*m;
  }
  __syncthreads();
  float m=red[8], r=rsqrtf(red[9]+1e-5f);
  __hip_bfloat16* op = out + (size_t)row*768;
  op[t]     = f2bf((x0-m)*r*g[t]     + b[t]);
  op[t+256] = f2bf((x1-m)*r*g[t+256] + b[t+256]);
  op[t+512] = f2bf((x2-m)*r*g[t+512] + b[t+512]);
}

// ---------------- GEMM: dbuf 2-phase, gload_lds w/ pre-swizzled source, swizzled ds_read ----
// C[M][N] = A[M][K] * BT[N][K]^T.
// EPI: 0=*0.125->bf16  1=KV split (+tem f32 on V)  2=+resid(f32)->f32  3=gelu->bf16  4=+resid(f32)->f32
template<int BM, int EPI>
__global__ __launch_bounds__(256) void gemm_gl(
    const __hip_bfloat16* __restrict__ A, const __hip_bfloat16* __restrict__ BT,
    const float* __restrict__ bias, int M, int N, int K,
    void* __restrict__ out, const void* __restrict__ aux0, void* __restrict__ out2){
  constexpr int NF = (BM==128)?4:2;
  __shared__ char sA[2][BM*128];
  __shared__ char sB[2][128*128];
  const int tid = threadIdx.x;
  const int l = tid & 63, w = tid >> 6;
  const int lg = l >> 4, li = l & 15;
  const int wrow = (BM==128)? (w>>1)*64 : 0;
  const int wcol = (BM==128)? (w&1)*64 : w*32;
  const int bm = blockIdx.x * BM;
  const int bn = blockIdx.y * 128;
  const int arow = w*(BM/4) + (l>>3);
  const int brow = w*32 + (l>>3);
  // pre-swizzled source element offset: LDS byte x=(l&7)*16 in row chunk (row&7 == l>>3)
  const int scol = ((((l&7)*16) ^ ((l>>3)<<4)) >> 1);

  auto stage = [&](int buf, int kt){
    const int k0 = kt*64;
#pragma unroll
    for(int i=0;i<BM/32;i++)
      gload16(A  + (size_t)(bm+arow+i*8)*K + k0 + scol, sA[buf] + (w*(BM/4))*128 + i*1024);
#pragma unroll
    for(int i=0;i<4;i++)
      gload16(BT + (size_t)(bn+brow+i*8)*K + k0 + scol, sB[buf] + (w*32)*128 + i*1024);
  };

  f32x4 acc[4][NF] = {};
  const int nk = K >> 6;
  stage(0, 0);
  __syncthreads();                 // drain prologue loads
  for(int kt=0; kt<nk; ++kt){
    const int cur = kt & 1;
    if(kt+1 < nk) stage(cur^1, kt+1);   // issue next-tile loads FIRST (in flight under MFMA)
#pragma unroll
    for(int kk=0;kk<2;kk++){
      const int kb = kk*64 + lg*16;
      bf16x8 af[4], bfr[NF];
#pragma unroll
      for(int m=0;m<4;m++){
        int row = wrow+m*16+li;
        af[m] = *(const bf16x8*)(sA[cur] + row*128 + (kb ^ ((row&7)<<4)));
      }
#pragma unroll
      for(int n=0;n<NF;n++){
        int row = wcol+n*16+li;
        bfr[n] = *(const bf16x8*)(sB[cur] + row*128 + (kb ^ ((row&7)<<4)));
      }
#pragma unroll
      for(int m=0;m<4;m++)
#pragma unroll
        for(int n=0;n<NF;n++)
          acc[m][n] = __builtin_amdgcn_mfma_f32_16x16x32_bf16(af[m], bfr[n], acc[m][n],0,0,0);
    }
    __syncthreads();               // drains vmcnt(0): next tile resident; cur reads done
  }
#pragma unroll
  for(int m=0;m<4;m++){
#pragma unroll
    for(int n=0;n<NF;n++){
#pragma unroll
      for(int r=0;r<4;r++){
        int row = bm + wrow + m*16 + lg*4 + r;
        int col = bn + wcol + n*16 + li;
        float v = acc[m][n][r] + bias[col];
        if constexpr(EPI==0){
          ((__hip_bfloat16*)out)[(size_t)row*N + col] = f2bf(v * 0.125f);
        } else if constexpr(EPI==1){
          if(col < 768){
            ((__hip_bfloat16*)out)[(size_t)row*768 + col] = f2bf(v);
          } else {
            int c = col - 768;
            int bb = row / 1344, ii = row % 1344;
            if(ii < 320) v += ((const float*)aux0)[((size_t)bb*320 + ii)*768 + c];
            ((__hip_bfloat16*)out2)[(size_t)row*768 + c] = f2bf(v);
          }
        } else if constexpr(EPI==2){
          v += ((const float*)aux0)[(size_t)row*N + col];
          ((float*)out)[(size_t)row*N + col] = v;
        } else if constexpr(EPI==3){
          float gl = 0.5f * v * (1.0f + erff(v * 0.70710678118654752f));
          ((__hip_bfloat16*)out)[(size_t)row*N + col] = f2bf(gl);
        } else {
          v += ((const float*)aux0)[(size_t)row*N + col];
          ((float*)out)[(size_t)row*N + col] = v;
        }
      }
    }
  }
}

// ---------------- fused attention: one block per (b, h, 64-row Q tile) ----------------
// K/V staged via global_load_lds with inverse-swizzled per-lane sources; single barrier per iter.
__global__ __launch_bounds__(256) void attn_kernel(
    const __hip_bfloat16* __restrict__ qh,  // (B*LQ, 768), pre-scaled by 0.125
    const __hip_bfloat16* __restrict__ kb,  // (B*LKV, 768)
    const __hip_bfloat16* __restrict__ vt,  // (B*H*64, 1344)  V transposed per (b,h)
    const float* __restrict__ pos,          // (H, LQ, LKV) f32
    __hip_bfloat16* __restrict__ xo){       // (B*LQ, 768)
  __shared__ char sK[2][8192];     // [kv][d] swizzled: byte x = d*2 ^ ((kv&7)<<4)
  __shared__ char sV[2][8192];     // [d][kv] swizzled: byte x = kv*2 ^ ((d&7)<<4)
  __shared__ char sP[4][2048];     // per-wave [q][kv] swizzled (wave-private)
  const int bid = blockIdx.x;
  const int qt = bid & 15, h = (bid >> 4) % 12, b = bid / 192;
  const int q0 = qt * 64;
  const int tid = threadIdx.x;
  const int l = tid & 63, w = tid >> 6;
  const int lg = l >> 4, li = l & 15;

  const int srow = w*16 + (l>>3);
  const int soff = (((l&7)*16) ^ ((l>>3)<<4)) >> 1;
  const __hip_bfloat16* ksrc = kb + ((size_t)b*1344 + srow)*768 + h*64 + soff;
  const __hip_bfloat16* vsrc = vt + ((size_t)(b*12+h)*64 + srow)*1344 + soff;

  bf16x8 aq[2];
  {
    const char* qp = (const char*)(qh + ((size_t)(b*1024 + q0 + w*16 + li))*768 + h*64);
    aq[0] = *(const bf16x8*)(qp + lg*16);
    aq[1] = *(const bf16x8*)(qp + 64 + lg*16);
  }
  const size_t posbase = ((size_t)h*1024 + q0 + w*16 + lg*4)*1344 + li;

  f32x4 accO[4] = {};
  float mrun[4], lrun[4];
#pragma unroll
  for(int r=0;r<4;r++){ mrun[r] = -1e30f; lrun[r] = 0.f; }

  auto stage = [&](int buf, int t){
    const size_t ko = (size_t)t*64*768;
    const size_t vo = (size_t)t*64;
    gload16(ksrc + ko,          sK[buf] + w*2048);
    gload16(ksrc + ko + 8*768,  sK[buf] + w*2048 + 1024);
    gload16(vsrc + vo,          sV[buf] + w*2048);
    gload16(vsrc + vo + 8*1344, sV[buf] + w*2048 + 1024);
  };
  auto ldpos = [&](int t, float pr[4][4]){
    const float* pp = pos + posbase + (size_t)t*64;
#pragma unroll
    for(int n=0;n<4;n++)
#pragma unroll
      for(int r=0;r<4;r++)
        pr[n][r] = __builtin_nontemporal_load(pp + (size_t)r*1344 + n*16);
  };

  float posr[4][4];
  ldpos(0, posr);
  stage(0, 0);
  __syncthreads();

  char* sPw = sP[w];
  for(int t=0; t<21; ++t){
    const int cur = t & 1;
    f32x4 accS[4] = {};
#pragma unroll
    for(int kk=0; kk<2; ++kk){
      const int kbyte = kk*64 + lg*16;
#pragma unroll
      for(int n=0;n<4;n++){
        int row = n*16 + li;
        bf16x8 bkf = *(const bf16x8*)(sK[cur] + row*128 + (kbyte ^ ((row&7)<<4)));
        accS[n] = __builtin_amdgcn_mfma_f32_16x16x32_bf16(aq[kk], bkf, accS[n], 0,0,0);
      }
    }
    if(t < 20) stage(cur^1, t+1);
    float npos[4][4];
    if(t < 20) ldpos(t+1, npos);

    float p[4][4], mt[4];
#pragma unroll
    for(int r=0;r<4;r++) mt[r] = -1e30f;
#pragma unroll
    for(int n=0;n<4;n++)
#pragma unroll
      for(int r=0;r<4;r++){
        float s = accS[n][r] + posr[n][r];
        p[n][r] = s;
        mt[r] = fmaxf(mt[r], s);
      }
#pragma unroll
    for(int r=0;r<4;r++){
#pragma unroll
      for(int o=1;o<16;o<<=1) mt[r] = fmaxf(mt[r], __shfl_xor(mt[r], o));
      float mnew = fmaxf(mrun[r], mt[r]);
      float sf = __expf(mrun[r]-mnew);
      mrun[r] = mnew;
      lrun[r] *= sf;
#pragma unroll
      for(int n=0;n<4;n++) accO[n][r] *= sf;
      float rs = 0.f;
#pragma unroll
      for(int n=0;n<4;n++){ p[n][r] = __expf(p[n][r]-mnew); rs += p[n][r]; }
#pragma unroll
      for(int o=1;o<16;o<<=1) rs += __shfl_xor(rs, o);
      lrun[r] += rs;
    }
#pragma unroll
    for(int n=0;n<4;n++)
#pragma unroll
      for(int r=0;r<4;r++){
        int qi = lg*4 + r, kj = n*16 + li;
        *(__hip_bfloat16*)(sPw + qi*128 + ((kj*2) ^ ((qi&7)<<4))) = f2bf(p[n][r]);
      }
#pragma unroll
    for(int kk=0; kk<2; ++kk){
      const int kbyte = kk*64 + lg*16;
      bf16x8 pa = *(const bf16x8*)(sPw + li*128 + (kbyte ^ ((li&7)<<4)));
#pragma unroll
      for(int n=0;n<4;n++){
        int d = n*16 + li;
        bf16x8 bvf = *(const bf16x8*)(sV[cur] + d*128 + (kbyte ^ ((d&7)<<4)));
        accO[n] = __builtin_amdgcn_mfma_f32_16x16x32_bf16(pa, bvf, accO[n], 0,0,0);
      }
    }
    if(t < 20){
#pragma unroll
      for(int n=0;n<4;n++)
#pragma unroll
        for(int r=0;r<4;r++) posr[n][r] = npos[n][r];
    }
    __syncthreads();
  }
#pragma unroll
  for(int n=0;n<4;n++)
#pragma unroll
    for(int r=0;r<4;r++){
      int row = b*1024 + q0 + w*16 + lg*4 + r;
      int col = h*64 + n*16 + li;
      xo[(size_t)row*768 + col] = f2bf(accO[n][r] / lrun[r]);
    }
}

extern "C" void kernel_launch(void* const* d_in, const int* in_sizes, int n_in,
                              void* d_out, int out_size, void* d_ws, size_t ws_size,
                              hipStream_t stream){
  const float* tem   = (const float*)d_in[0];
  const float* qin   = (const float*)d_in[1];
  const float* kvin  = (const float*)d_in[2];
  const float* pos   = (const float*)d_in[3];
  const float* ln1qg = (const float*)d_in[4];
  const float* ln1qb = (const float*)d_in[5];
  const float* ln1kg = (const float*)d_in[6];
  const float* ln1kb = (const float*)d_in[7];
  const float* Wq    = (const float*)d_in[8];
  const float* bq    = (const float*)d_in[9];
  const float* Wkv   = (const float*)d_in[10];
  const float* bkv   = (const float*)d_in[11];
  const float* Wp    = (const float*)d_in[12];
  const float* bp    = (const float*)d_in[13];
  const float* ln2g  = (const float*)d_in[14];
  const float* ln2b  = (const float*)d_in[15];
  const float* W1    = (const float*)d_in[16];
  const float* b1    = (const float*)d_in[17];
  const float* W2    = (const float*)d_in[18];
  const float* b2    = (const float*)d_in[19];

  char* ws = (char*)d_ws; size_t off = 0;
  auto alloc = [&](size_t n){ char* p = ws + off; off = (off + n + 255) & ~(size_t)255; return p; };
  __hip_bfloat16* WqT  = (__hip_bfloat16*)alloc((size_t)768*768*2);
  __hip_bfloat16* WkvT = (__hip_bfloat16*)alloc((size_t)1536*768*2);
  __hip_bfloat16* WpT  = (__hip_bfloat16*)alloc((size_t)768*768*2);
  __hip_bfloat16* W1T  = (__hip_bfloat16*)alloc((size_t)3072*768*2);
  __hip_bfloat16* W2T  = (__hip_bfloat16*)alloc((size_t)768*3072*2);
  __hip_bfloat16* qn   = (__hip_bfloat16*)alloc((size_t)4096*768*2);
  char* poolBase = alloc((size_t)5376*768*2*3 + (size_t)4096*768*2); // kvn,kbuf,vbuf,qhb pool
  __hip_bfloat16* kvn  = (__hip_bfloat16*)poolBase;
  __hip_bfloat16* kbuf = kvn  + (size_t)5376*768;
  __hip_bfloat16* vbuf = kbuf + (size_t)5376*768;
  __hip_bfloat16* qhb  = vbuf + (size_t)5376*768;
  __hip_bfloat16* xat  = (__hip_bfloat16*)alloc((size_t)4096*768*2);
  float*          x1f  = (float*)alloc((size_t)4096*768*4);
  __hip_bfloat16* vt   = kvn;   // kvn dead after gemm<1>
  __hip_bfloat16* hln  = qn;    // qn dead after gemm<0>
  __hip_bfloat16* h1   = kvn;   // pool dead after attn

  dim3 tb(32,8);
  transpose_f2b<<<dim3(768/32, 768/32),  tb, 0, stream>>>(Wq,  WqT,  768, 768);
  transpose_f2b<<<dim3(1536/32, 768/32), tb, 0, stream>>>(Wkv, WkvT, 768, 1536);
  transpose_f2b<<<dim3(768/32, 768/32),  tb, 0, stream>>>(Wp,  WpT,  768, 768);
  transpose_f2b<<<dim3(3072/32, 768/32), tb, 0, stream>>>(W1,  W1T,  768, 3072);
  transpose_f2b<<<dim3(768/32, 3072/32), tb, 0, stream>>>(W2,  W2T,  3072, 768);

  ln_kernel<<<4096, 256, 0, stream>>>(qin,  ln1qg, ln1qb, qn);
  ln_kernel<<<5376, 256, 0, stream>>>(kvin, ln1kg, ln1kb, kvn);

  gemm_gl<64,0> <<<dim3(64, 6),  256, 0, stream>>>(qn,  WqT,  bq,  4096, 768,  768,  qhb, nullptr, nullptr);
  gemm_gl<128,1><<<dim3(42, 12), 256, 0, stream>>>(kvn, WkvT, bkv, 5376, 1536, 768,  kbuf, tem, vbuf);
  transpose_vt<<<dim3(48, 21), 256, 0, stream>>>(vbuf, vt);

  attn_kernel<<<768, 256, 0, stream>>>(qhb, kbuf, vt, pos, xat);

  gemm_gl<64,2> <<<dim3(64, 6),  256, 0, stream>>>(xat, WpT,  bp,  4096, 768,  768,  x1f, qin, nullptr);
  ln_kernel<<<4096, 256, 0, stream>>>(x1f, ln2g, ln2b, hln);
  gemm_gl<128,3><<<dim3(32, 24), 256, 0, stream>>>(hln, W1T,  b1,  4096, 3072, 768,  h1, nullptr, nullptr);
  gemm_gl<64,4> <<<dim3(64, 6),  256, 0, stream>>>(h1,  W2T,  b2,  4096, 768,  3072, (float*)d_out, x1f, nullptr);
}